// Round 2
// 1440.244 us; speedup vs baseline: 1.0545x; 1.0545x over previous
//
#include <hip/hip_runtime.h>

// ---------------------------------------------------------------------------
// TransformerBlock: B=2 L=2048 D=2048 H=16 HD=128, fp32 in/out.
// bf16 MFMA gemm_bt (m97 structure) for all 6 matmuls.
// Softmax is FUSED: QK epilogue writes e=exp(v*scale) to the scores region and
// atomically accumulates per-row sums; PV staging multiplies by 1/rowsum,
// writes normalized p back in place (each element touched by exactly one
// block), and feeds bf16 p to the MFMA. No separate softmax pass.
// (Resubmission of round-1 kernel: prior run died to container infra flake,
// not a kernel verdict.)
// ---------------------------------------------------------------------------

typedef __bf16 bf16;
typedef bf16 bf16x4 __attribute__((ext_vector_type(4)));
typedef bf16 bf16x8 __attribute__((ext_vector_type(8)));
typedef float f32x4 __attribute__((ext_vector_type(4)));

#define AS1 __attribute__((address_space(1)))
#define AS3 __attribute__((address_space(3)))

__device__ __forceinline__ void load_lds16(const bf16* g, bf16* l) {
  __builtin_amdgcn_global_load_lds((AS1 void*)g, (AS3 void*)l, 16, 0, 0);
}

// zero 65536 floats (rowsum buffer); grid 256 x 256 threads
__global__ __launch_bounds__(256) void zero_k(float* __restrict__ p) {
  p[blockIdx.x * 256 + threadIdx.x] = 0.f;
}

// fp32 -> bf16 elementwise convert (n multiple of 4)
__global__ __launch_bounds__(256) void f2b(const float* __restrict__ in,
                                           bf16* __restrict__ out, long n) {
  long i = ((long)blockIdx.x * 256 + threadIdx.x) * 4;
  if (i >= n) return;
  float4 v = *(const float4*)(in + i);
  bf16x4 o = {(bf16)v.x, (bf16)v.y, (bf16)v.z, (bf16)v.w};
  *(bf16x4*)(out + i) = o;
}

// RMSNorm over D=2048, one block (256 thr) per row; output bf16.
__global__ __launch_bounds__(256) void rmsnorm_k(const float* __restrict__ x,
                                                 const float* __restrict__ g,
                                                 bf16* __restrict__ o) {
  const long row = blockIdx.x;
  const float* xr = x + row * 2048;
  const int base = threadIdx.x * 8;
  float4 a = *(const float4*)(xr + base);
  float4 b = *(const float4*)(xr + base + 4);
  float ss = a.x * a.x + a.y * a.y + a.z * a.z + a.w * a.w +
             b.x * b.x + b.y * b.y + b.z * b.z + b.w * b.w;
  for (int off = 32; off; off >>= 1) ss += __shfl_down(ss, off, 64);
  __shared__ float red[4];
  const int lane = threadIdx.x & 63, wv = threadIdx.x >> 6;
  if (lane == 0) red[wv] = ss;
  __syncthreads();
  const float tot = red[0] + red[1] + red[2] + red[3];
  const float nrm = rsqrtf(tot * (1.0f / 2048.0f) + 1e-6f);
  float4 ga = *(const float4*)(g + base);
  float4 gb = *(const float4*)(g + base + 4);
  bf16x8 ov = {(bf16)(a.x * nrm * ga.x), (bf16)(a.y * nrm * ga.y),
               (bf16)(a.z * nrm * ga.z), (bf16)(a.w * nrm * ga.w),
               (bf16)(b.x * nrm * gb.x), (bf16)(b.y * nrm * gb.y),
               (bf16)(b.z * nrm * gb.z), (bf16)(b.w * nrm * gb.w)};
  *(bf16x8*)(o + row * 2048 + base) = ov;
}

// Transpose V: vt[z][d][s] = qkv[(z>>4)*2048 + s][4096 + (z&15)*128 + d]
__global__ __launch_bounds__(256) void transpose_v(const bf16* __restrict__ qkv,
                                                   bf16* __restrict__ vt) {
  __shared__ bf16 t[32][33];
  const int z = blockIdx.z, zb = z >> 4, zh = z & 15;
  const int s0 = blockIdx.x * 32, d0 = blockIdx.y * 32;
  const int tx = threadIdx.x & 31, ty = threadIdx.x >> 5;  // ty in 0..7
#pragma unroll
  for (int i = 0; i < 32; i += 8)
    t[ty + i][tx] =
        qkv[(long)(zb * 2048 + s0 + ty + i) * 6144 + 4096 + zh * 128 + d0 + tx];
  __syncthreads();
#pragma unroll
  for (int i = 0; i < 32; i += 8)
    vt[(long)z * 262144 + (long)(d0 + ty + i) * 2048 + s0 + tx] = t[tx][ty + i];
}

// ---------------------------------------------------------------------------
// C = A * B^T  (both operands K-major). 128x128 tile, 256 thr = 4 waves,
// each wave a 64x64 subtile as 4x4 of 16x16x32 bf16 MFMAs. Batched via
// blockIdx.z with (b,h)-decomposed strides.
// AMODE 0: A bf16 via global_load_lds.
// AMODE 2: A fp32 = e values; p = e * (1/rowsum[row]) computed during reg
//          staging, p stored back IN PLACE (final softmax output), (bf16)p
//          into LDS for the MFMA. p-stores issued after the staging barrier
//          so they drain under the MFMA phase. Rows-per-z hardcoded 2048.
// EXPM 1:  epilogue writes e = exp(v*scale) fp32 and atomicAdds per-row
//          partial sums of e into rowsum[z*2048 + row].
// Else epilogue: *scale, +addf (fp32, C layout), *mulb (bf16, C layout),
// relu, store fp32 (Cf) or bf16 (Cb).
// ---------------------------------------------------------------------------
template <int AMODE, int EXPM>
__global__ __launch_bounds__(256) void gemm_bt(
    const void* __restrict__ Ap, long lda, long sAb, long sAh,
    const bf16* __restrict__ Bt, long ldb, long sBb, long sBh, int K,
    float* __restrict__ Cf, bf16* __restrict__ Cb, long ldc, long sCb, long sCh,
    float scale, const float* __restrict__ addf, const bf16* __restrict__ mulb,
    int relu, float* rowsum, float* Awr) {
  __shared__ __align__(16) bf16 ldsA[128 * 32];
  __shared__ __align__(16) bf16 ldsB[128 * 32];

  const int tid = threadIdx.x;
  const int lane = tid & 63;
  const int wv = tid >> 6;
  const int wm = (wv >> 1) << 6;
  const int wn = (wv & 1) << 6;
  const int fr = lane & 15;
  const int ko = (lane >> 4) << 3;

  const long m0 = (long)blockIdx.x * 128;
  const long n0 = (long)blockIdx.y * 128;
  const int zb = blockIdx.z >> 4, zh = blockIdx.z & 15;

  const bf16* Abf = nullptr;
  const float* Af = nullptr;
  float* Aw = nullptr;
  if constexpr (AMODE == 0) {
    Abf = (const bf16*)Ap + (long)zb * sAb + (long)zh * sAh;
  } else {
    Af = (const float*)Ap + (long)zb * sAb + (long)zh * sAh;
    Aw = Awr + (long)zb * sAb + (long)zh * sAh;
  }
  const bf16* B = Bt + (long)zb * sBb + (long)zh * sBh;

  // staging chunk assignment: 512 16B-chunks per tile, thread covers c, c+256
  const int c0 = tid, c1 = tid + 256;
  const int r0 = c0 >> 2, kk0 = (c0 & 3) << 3;
  const int r1 = c1 >> 2, kk1 = (c1 & 3) << 3;

  float inv0 = 0.f, inv1 = 0.f;
  if constexpr (AMODE == 2) {
    const long rb = (long)blockIdx.z * 2048;
    inv0 = 1.0f / rowsum[rb + m0 + r0];
    inv1 = 1.0f / rowsum[rb + m0 + r1];
  }

  f32x4 acc[4][4] = {};

  for (int k0 = 0; k0 < K; k0 += 32) {
    float4 u0, v0, u1, v1;
    if constexpr (AMODE == 2) {
      const float* g0 = Af + (m0 + r0) * lda + k0 + kk0;
      u0 = *(const float4*)g0;
      v0 = *(const float4*)(g0 + 4);
      const float* g1 = Af + (m0 + r1) * lda + k0 + kk1;
      u1 = *(const float4*)g1;
      v1 = *(const float4*)(g1 + 4);
      u0.x *= inv0; u0.y *= inv0; u0.z *= inv0; u0.w *= inv0;
      v0.x *= inv0; v0.y *= inv0; v0.z *= inv0; v0.w *= inv0;
      u1.x *= inv1; u1.y *= inv1; u1.z *= inv1; u1.w *= inv1;
      v1.x *= inv1; v1.y *= inv1; v1.z *= inv1; v1.w *= inv1;
      bf16x8 w0 = {(bf16)u0.x, (bf16)u0.y, (bf16)u0.z, (bf16)u0.w,
                   (bf16)v0.x, (bf16)v0.y, (bf16)v0.z, (bf16)v0.w};
      bf16x8 w1 = {(bf16)u1.x, (bf16)u1.y, (bf16)u1.z, (bf16)u1.w,
                   (bf16)v1.x, (bf16)v1.y, (bf16)v1.z, (bf16)v1.w};
      *(bf16x8*)&ldsA[c0 * 8] = w0;
      *(bf16x8*)&ldsA[c1 * 8] = w1;
    } else {
      load_lds16(Abf + (m0 + r0) * lda + k0 + kk0, &ldsA[c0 * 8]);
      load_lds16(Abf + (m0 + r1) * lda + k0 + kk1, &ldsA[c1 * 8]);
    }
    load_lds16(B + (n0 + r0) * ldb + k0 + kk0, &ldsB[c0 * 8]);
    load_lds16(B + (n0 + r1) * ldb + k0 + kk1, &ldsB[c1 * 8]);
    __syncthreads();

    if constexpr (AMODE == 2) {
      // normalized-p writeback, overlapped with the MFMA phase below
      float* s0 = Aw + (m0 + r0) * lda + k0 + kk0;
      *(float4*)s0 = u0;
      *(float4*)(s0 + 4) = v0;
      float* s1 = Aw + (m0 + r1) * lda + k0 + kk1;
      *(float4*)s1 = u1;
      *(float4*)(s1 + 4) = v1;
    }

    bf16x8 af[4], bfr[4];
#pragma unroll
    for (int i = 0; i < 4; ++i)
      af[i] = *(const bf16x8*)&ldsA[(wm + i * 16 + fr) * 32 + ko];
#pragma unroll
    for (int j = 0; j < 4; ++j)
      bfr[j] = *(const bf16x8*)&ldsB[(wn + j * 16 + fr) * 32 + ko];
#pragma unroll
    for (int i = 0; i < 4; ++i)
#pragma unroll
      for (int j = 0; j < 4; ++j)
        acc[i][j] =
            __builtin_amdgcn_mfma_f32_16x16x32_bf16(af[i], bfr[j], acc[i][j], 0, 0, 0);
    __syncthreads();
  }

  // C/D layout (verified m89/m91): col = lane&15, row = (lane>>4)*4 + reg
  const long coff = (long)zb * sCb + (long)zh * sCh;
  if constexpr (EXPM) {
    const long rb = (long)blockIdx.z * 2048;
#pragma unroll
    for (int i = 0; i < 4; ++i) {
#pragma unroll
      for (int r = 0; r < 4; ++r) {
        const long row = m0 + wm + i * 16 + ((lane >> 4) << 2) + r;
        float es = 0.f;
#pragma unroll
        for (int j = 0; j < 4; ++j) {
          const long col = n0 + wn + j * 16 + (lane & 15);
          const float e = __expf(acc[i][j][r] * scale);
          Cf[coff + row * ldc + col] = e;
          es += e;
        }
        // reduce across the 16 lanes sharing this row (xor masks < 16)
        es += __shfl_xor(es, 1, 64);
        es += __shfl_xor(es, 2, 64);
        es += __shfl_xor(es, 4, 64);
        es += __shfl_xor(es, 8, 64);
        if ((lane & 15) == 0) atomicAdd(rowsum + rb + row, es);
      }
    }
  } else {
#pragma unroll
    for (int i = 0; i < 4; ++i) {
#pragma unroll
      for (int r = 0; r < 4; ++r) {
        const long row = m0 + wm + i * 16 + ((lane >> 4) << 2) + r;
#pragma unroll
        for (int j = 0; j < 4; ++j) {
          const long col = n0 + wn + j * 16 + (lane & 15);
          const long idx = coff + row * ldc + col;
          float v = acc[i][j][r] * scale;
          if (addf) v += addf[idx];
          if (mulb) v *= (float)mulb[idx];
          if (relu) v = fmaxf(v, 0.f);
          if (Cf)
            Cf[idx] = v;
          else
            Cb[idx] = (bf16)v;
        }
      }
    }
  }
}

extern "C" void kernel_launch(void* const* d_in, const int* in_sizes, int n_in,
                              void* d_out, int out_size, void* d_ws,
                              size_t ws_size, hipStream_t stream) {
  (void)in_sizes; (void)n_in; (void)out_size; (void)ws_size;
  const float* x      = (const float*)d_in[0];
  const float* w_qkv  = (const float*)d_in[1];
  const float* w_out  = (const float*)d_in[2];
  const float* w_in   = (const float*)d_in[3];
  const float* w_hid  = (const float*)d_in[4];
  const float* w_gate = (const float*)d_in[5];
  const float* g_attn = (const float*)d_in[6];
  const float* g_ffn  = (const float*)d_in[7];

  float* outp   = (float*)d_out;       // [4096 x 2048] fp32
  float* scores = outp + 8388608;      // [32 x 2048 x 2048] fp32

  // workspace layout (bytes). peak = 142,606,336 (unchanged)
  char* ws = (char*)d_ws;
  bf16* wbuf   = (bf16*)(ws);                    // 25,165,824 (weight bf16 scratch)
  bf16* xn     = (bf16*)(ws + 25165824);         // 16,777,216 (also vt, yn)
  bf16* qkvb   = (bf16*)(ws + 41943040);         // 50,331,648 (later: hidden)
  bf16* attnb  = (bf16*)(ws + 92274688);         // 16,777,216
  float* after = (float*)(ws + 109051904);       // 33,554,432
  bf16* vt     = xn;                             // reuse (xn dead after qkv gemm)
  bf16* yn     = xn;                             // reuse (vt dead after PV)
  bf16* hidden = qkvb;                           // reuse (qkv dead after PV)
  bf16* hg     = (bf16*)(ws + 58720256);         // inside old qkv region
  // rowsum[65536] aliases head of `after` — live only between zero_k and PV,
  // `after` is first written at step 6 (post-PV). Stream-ordered, safe.
  float* rowsum = after;

  dim3 blk(256);

  // 0) rowsum = 0 (65536 rows)
  zero_k<<<256, blk, 0, stream>>>(rowsum);

  // 1) w_qkv -> bf16 ; xn = rmsnorm(x)
  f2b<<<12288, blk, 0, stream>>>(w_qkv, wbuf, 12582912L);
  rmsnorm_k<<<4096, blk, 0, stream>>>(x, g_attn, xn);

  // 2) qkv = xn @ w_qkv^T   [4096 x 6144] bf16
  gemm_bt<0, 0><<<dim3(32, 48, 1), blk, 0, stream>>>(
      (const void*)xn, 2048L, 0L, 0L, wbuf, 2048L, 0L, 0L, 2048,
      (float*)nullptr, qkvb, 6144L, 0L, 0L, 1.0f, nullptr, nullptr, 0,
      nullptr, nullptr);

  // 3) V transpose -> vt[z][128][2048]
  transpose_v<<<dim3(64, 4, 32), blk, 0, stream>>>(qkvb, vt);

  // 4) scores <- e = exp(QK^T/sqrt(128)) fp32; rowsum += per-row sums
  gemm_bt<0, 1><<<dim3(16, 16, 32), blk, 0, stream>>>(
      (const void*)qkvb, 6144L, 12582912L, 128L,
      qkvb + 2048, 6144L, 12582912L, 128L, 128,
      scores, (bf16*)nullptr, 2048L, 67108864L, 4194304L,
      0.08838834764831845f, nullptr, nullptr, 0, rowsum, nullptr);

  // 5) attn = P @ V ; P = e/rowsum computed in staging, written back in place
  gemm_bt<2, 0><<<dim3(16, 1, 32), blk, 0, stream>>>(
      (const void*)scores, 2048L, 67108864L, 4194304L,
      vt, 2048L, 4194304L, 262144L, 2048,
      (float*)nullptr, attnb, 2048L, 4194304L, 128L, 1.0f, nullptr, nullptr, 0,
      rowsum, scores);

  // 6) after = x + attn @ w_out^T   (fp32)
  f2b<<<4096, blk, 0, stream>>>(w_out, wbuf, 4194304L);
  gemm_bt<0, 0><<<dim3(32, 16, 1), blk, 0, stream>>>(
      (const void*)attnb, 2048L, 0L, 0L, wbuf, 2048L, 0L, 0L, 2048,
      after, (bf16*)nullptr, 2048L, 0L, 0L, 1.0f, x, nullptr, 0,
      nullptr, nullptr);

  // 7) yn = rmsnorm(after)
  rmsnorm_k<<<4096, blk, 0, stream>>>(after, g_ffn, yn);

  // 8) hidden = relu(yn @ w_in^T)  bf16
  f2b<<<4096, blk, 0, stream>>>(w_in, wbuf, 4194304L);
  gemm_bt<0, 0><<<dim3(32, 16, 1), blk, 0, stream>>>(
      (const void*)yn, 2048L, 0L, 0L, wbuf, 2048L, 0L, 0L, 2048,
      (float*)nullptr, hidden, 2048L, 0L, 0L, 1.0f, nullptr, nullptr, 1,
      nullptr, nullptr);

  // 9) hg = hidden * (hidden @ w_gate^T)  bf16
  f2b<<<4096, blk, 0, stream>>>(w_gate, wbuf, 4194304L);
  gemm_bt<0, 0><<<dim3(32, 16, 1), blk, 0, stream>>>(
      (const void*)hidden, 2048L, 0L, 0L, wbuf, 2048L, 0L, 0L, 2048,
      (float*)nullptr, hg, 2048L, 0L, 0L, 1.0f, nullptr, hidden, 0,
      nullptr, nullptr);

  // 10) out = after + hg @ w_hidden^T  (fp32 -> d_out)
  f2b<<<4096, blk, 0, stream>>>(w_hid, wbuf, 4194304L);
  gemm_bt<0, 0><<<dim3(32, 16, 1), blk, 0, stream>>>(
      (const void*)hg, 2048L, 0L, 0L, wbuf, 2048L, 0L, 0L, 2048,
      outp, (bf16*)nullptr, 2048L, 0L, 0L, 1.0f, after, nullptr, 0,
      nullptr, nullptr);
}